// Round 6
// baseline (264.376 us; speedup 1.0000x reference)
//
#include <hip/hip_runtime.h>

// ---------- problem dims ----------
constexpr int B_ = 16, C_ = 64, F_ = 40, T_ = 512;
constexpr int D_ = F_ * C_;              // 2560
constexpr float SCALE = 0.019764235376052372f;  // 1/sqrt(2560), baked into G

// ---------- types ----------
typedef __attribute__((ext_vector_type(8))) short s16x8;
typedef __attribute__((ext_vector_type(4))) short s16x4;
typedef __attribute__((ext_vector_type(4))) float f32x4;

static __device__ __forceinline__ short f2bf(float f) {
  union { float f; unsigned u; } v; v.f = f;
  unsigned r = v.u + 0x7fffu + ((v.u >> 16) & 1u);   // RNE, no NaN inputs
  return (short)(r >> 16);
}

static __device__ __forceinline__ f32x4 mfma16(s16x8 a, s16x8 b, f32x4 c) {
  return __builtin_amdgcn_mfma_f32_16x16x32_bf16(a, b, c, 0, 0, 0);
}

// async 16B global->LDS (wave-uniform LDS base + lane*16 placement)
static __device__ __forceinline__ void gl2lds16(const short* g, short* l) {
  __builtin_amdgcn_global_load_lds(
      (const __attribute__((address_space(1))) unsigned int*)g,
      (__attribute__((address_space(3))) unsigned int*)l, 16, 0, 0);
}

// =====================================================================
// Kernel 0 (prep): blocks 0-1 convert Wv -> fragment-ordered bf16 Wb.
// Block 2 computes Gt = fragment-ordered bf16 of A[m=c'][k=c] =
// SCALE * sum_o Wq[o,k] * Wk[o,m]  (i.e. G[c,c'] with m=c', k=c), in
// full fp32, and zeroes the rowsum accumulator.
// =====================================================================
__global__ __launch_bounds__(256) void prep_kernel(
    const float* __restrict__ Wq, const float* __restrict__ Wk,
    const float* __restrict__ Wv, short* __restrict__ Wb,
    short* __restrict__ Gt, float* __restrict__ rowsum)
{
  __shared__ float lq[4096], lk[4096];    // used by block 2 only
  const int blk = blockIdx.x, tid = threadIdx.x;
  if (blk < 2) {
    const int n = blk * 256 + tid;        // 0..511 fragment granule
    const int mi = n >> 7, ks = (n >> 6) & 1, lane = n & 63;
    const int o = mi * 16 + (lane & 15);
    const int cb = ks * 32 + (lane >> 4) * 8;
    const float4 a = *(const float4*)(Wv + o * 64 + cb);
    const float4 b2 = *(const float4*)(Wv + o * 64 + cb + 4);
    s16x8 s;
    s[0] = f2bf(a.x);  s[1] = f2bf(a.y);
    s[2] = f2bf(a.z);  s[3] = f2bf(a.w);
    s[4] = f2bf(b2.x); s[5] = f2bf(b2.y);
    s[6] = f2bf(b2.z); s[7] = f2bf(b2.w);
    *(s16x8*)&Wb[n * 8] = s;
  } else {
    for (int i = tid; i < 1024; i += 256) {
      *(float4*)&lq[i * 4] = *(const float4*)(Wq + i * 4);
      *(float4*)&lk[i * 4] = *(const float4*)(Wk + i * 4);
    }
    __syncthreads();
    #pragma unroll
    for (int gi = 0; gi < 2; ++gi) {
      const int g = gi * 256 + tid;       // 0..511
      const int mi = g >> 7, ks = (g >> 6) & 1, lane = g & 63;
      const int cm = mi * 16 + (lane & 15);      // m = c'
      const int cb = ks * 32 + (lane >> 4) * 8;  // k-base = c
      float s[8] = {};
      for (int o = 0; o < 64; ++o) {
        const float ko = lk[o * 64 + cm];
        const float4 a0 = *(const float4*)&lq[o * 64 + cb];
        const float4 a1 = *(const float4*)&lq[o * 64 + cb + 4];
        s[0] += a0.x * ko; s[1] += a0.y * ko; s[2] += a0.z * ko; s[3] += a0.w * ko;
        s[4] += a1.x * ko; s[5] += a1.y * ko; s[6] += a1.z * ko; s[7] += a1.w * ko;
      }
      s16x8 sv;
      #pragma unroll
      for (int j = 0; j < 8; ++j) sv[j] = f2bf(s[j] * SCALE);
      *(s16x8*)&Gt[g * 8] = sv;
    }
    for (int i = tid; i < B_ * T_; i += 256) rowsum[i] = 0.0f;
  }
}

// =====================================================================
// Kernel 1: v7 proj.  Q,K GEMMs deleted (G-algebra): per (b,f,t-tile)
//  - stage X [64c][128t] bf16 in LDS (proven path)
//  - transpose-store Xb[b][t][f*64+c] via Ost full-line path (no GEMM)
//  - V = Wv GEMM (swapped-operand) + transpose-store (proven path)
// Writes 84 MB instead of 126; 16 MFMA/wave instead of 48; 6 barriers.
// =====================================================================
__global__ __launch_bounds__(256, 2) void proj_kernel(
    const float* __restrict__ x, const short* __restrict__ Wb,
    short* __restrict__ Xb, short* __restrict__ V)
{
  constexpr int XS = 132;   // X lds row stride (shorts)
  __shared__ __align__(16) short Xl[64 * XS];   // 16.9 KB; reused as Ost
  char* Ost = (char*)Xl;                        // store-staging view

  const int b = blockIdx.z, f = blockIdx.y, tt = blockIdx.x;  // tt: 0..3
  const int tid = threadIdx.x;

  // ---- stage X tile [64 c][128 t] as bf16 (coalesced float4 loads) ----
  const float* xp = x + (((size_t)b * 64) * 40 + f) * 512 + tt * 128;
  #pragma unroll
  for (int it = 0; it < 8; ++it) {
    const int i = tid + it * 256;
    const int c = i >> 5, j = i & 31;
    const float4 v4 = *(const float4*)(xp + (size_t)c * (F_ * T_) + j * 4);
    s16x4 s4; s4[0] = f2bf(v4.x); s4[1] = f2bf(v4.y);
    s4[2] = f2bf(v4.z); s4[3] = f2bf(v4.w);
    *(s16x4*)&Xl[c * XS + j * 4] = s4;
  }
  __syncthreads();

  const int w = tid >> 6, lane = tid & 63;
  const int quad = lane >> 4, c16 = lane & 15;
  const int tl = w * 32;

  // X fragments (0-conflict reads): bfrag[ni][ks][j] = X[c=ks*32+quad*8+j][t]
  s16x8 bfrag[2][2];
  #pragma unroll
  for (int ni = 0; ni < 2; ++ni)
    #pragma unroll
    for (int ks = 0; ks < 2; ++ks) {
      const int t = tl + ni * 16 + c16;
      const int cb = ks * 32 + quad * 8;
      s16x8 tmp;
      #pragma unroll
      for (int j = 0; j < 8; ++j) tmp[j] = Xl[(cb + j) * XS + t];
      bfrag[ni][ks] = tmp;
    }
  __syncthreads();   // Xl dead -> Ost

  // ---- Xb path: bfrag -> Ost[t][c] (XOR-swizzled), full-line store ----
  #pragma unroll
  for (int ni = 0; ni < 2; ++ni)
    #pragma unroll
    for (int ks = 0; ks < 2; ++ks) {
      const int trow = tl + ni * 16 + c16;          // 0..127
      unsigned addr = trow * 128 + ks * 64 + quad * 16;
      addr ^= (unsigned)((trow & 7) << 4);
      *(s16x8*)(Ost + addr) = bfrag[ni][ks];
    }
  __syncthreads();
  #pragma unroll
  for (int pass = 0; pass < 4; ++pass) {
    const int row = pass * 32 + (tid >> 3);
    const int s16off = tid & 7;
    unsigned a2 = row * 128 + s16off * 16;
    a2 ^= (unsigned)((row & 7) << 4);
    const s16x8 vz = *(const s16x8*)(Ost + a2);
    *(s16x8*)&Xb[(size_t)(b * 512 + tt * 128 + row) * D_ + f * 64 + s16off * 8] = vz;
  }
  __syncthreads();   // Ost dead

  // ---- V path: swapped-operand GEMM, D[m=t][n=o] ----
  s16x8 wfrag[4][2];
  #pragma unroll
  for (int mi = 0; mi < 4; ++mi)
    #pragma unroll
    for (int ks = 0; ks < 2; ++ks)
      wfrag[mi][ks] = *(const s16x8*)(Wb + ((mi * 2 + ks) * 64 + lane) * 8);

  f32x4 acc[2][4] = {};
  #pragma unroll
  for (int ks = 0; ks < 2; ++ks)
    #pragma unroll
    for (int ni = 0; ni < 2; ++ni)
      #pragma unroll
      for (int mi = 0; mi < 4; ++mi)
        acc[ni][mi] = mfma16(bfrag[ni][ks], wfrag[mi][ks], acc[ni][mi]);
  // acc -> Ost[o][t], rowstride 256B, XOR-swizzled
  #pragma unroll
  for (int ni = 0; ni < 2; ++ni)
    #pragma unroll
    for (int mi = 0; mi < 4; ++mi) {
      const int orow = mi * 16 + c16;               // 0..63
      unsigned addr = orow * 256 + (tl + ni * 16 + quad * 4) * 2;
      addr ^= (unsigned)((orow & 7) << 4);
      s16x4 s4;
      #pragma unroll
      for (int r = 0; r < 4; ++r) s4[r] = f2bf(acc[ni][mi][r]);
      *(s16x4*)(Ost + addr) = s4;
    }
  __syncthreads();
  #pragma unroll
  for (int pass = 0; pass < 4; ++pass) {
    const int row = pass * 16 + (tid >> 4);
    const int s16off = tid & 15;
    unsigned a2 = row * 256 + s16off * 16;
    a2 ^= (unsigned)((row & 7) << 4);
    const s16x8 vz = *(const s16x8*)(Ost + a2);
    *(s16x8*)&V[((size_t)(b * D_ + f * 64 + row)) * 512 + tt * 128 + s16off * 8] = vz;
  }
}

// =====================================================================
// Kernel 2: fused scores+softmax-numerator with inline G-transform.
// S-tile = (X_panel1 . G) . X_panel2^T summed over (f,c) K-dim 2560.
// R3-proven 64x128 geometry; per K-step the 64-row A-panel is
// transformed Y = X*G via 8 MFMA/wave into YA (8KB LDS), then the
// proven swizzled main loop runs with am from YA, bm from Bs.
// E = exp(S) stored bf16; per-row sums atomicAdd'ed into rowsum.
// =====================================================================
__global__ __launch_bounds__(256) void scores_kernel(
    const short* __restrict__ Xb, const short* __restrict__ Gt,
    short* __restrict__ A, float* __restrict__ rowsum)
{
  __shared__ __align__(16) short As[64 * 64];    // 8 KB  (raw X, A-panel)
  __shared__ __align__(16) short Bs[128 * 64];   // 16 KB (raw X, B-panel)
  __shared__ __align__(16) short YA[64 * 64];    // 8 KB  (X*G)
  const int b = blockIdx.y;
  const int mt = blockIdx.x >> 2, nt = blockIdx.x & 3;
  const int m0 = mt * 64, n0 = nt * 128;
  const int tid = threadIdx.x;
  const int w = tid >> 6, lane = tid & 63, quad = lane >> 4, c16 = lane & 15;
  const int wm = (w >> 1) * 32, wn = (w & 1) * 64;

  const short* qb = Xb + (size_t)(b * 512 + m0) * D_;
  const short* kb = Xb + (size_t)(b * 512 + n0) * D_;

  // G^T fragments (A-operand of transform), block-invariant
  s16x8 gt[4][2];
  #pragma unroll
  for (int mi = 0; mi < 4; ++mi)
    #pragma unroll
    for (int ks = 0; ks < 2; ++ks)
      gt[mi][ks] = *(const s16x8*)(Gt + ((mi * 2 + ks) * 64 + lane) * 8);

  // staging (swizzled placement, proven)
  const short* agp[2]; short* aldsb[2];
  #pragma unroll
  for (int i = 0; i < 2; ++i) {
    const int s = i * 256 + tid, row = s >> 3;
    const int g = (s & 7) ^ (row & 7);
    agp[i] = qb + (size_t)row * D_ + g * 8;
    aldsb[i] = &As[(i * 256 + w * 64) * 8];
  }
  const short* bgp[4]; short* bldsb[4];
  #pragma unroll
  for (int i = 0; i < 4; ++i) {
    const int s = i * 256 + tid, row = s >> 3;
    const int g = (s & 7) ^ (row & 7);
    bgp[i] = kb + (size_t)row * D_ + g * 8;
    bldsb[i] = &Bs[(i * 256 + w * 64) * 8];
  }

  // transform source frags: B[n=t1][k=c], t1 = w*16+c16 (wave owns 16 cols)
  const short* xrp[2];
  #pragma unroll
  for (int ks = 0; ks < 2; ++ks) {
    const int row = w * 16 + c16;
    const int g = (ks * 4 + quad) ^ (row & 7);
    xrp[ks] = &As[row * 64 + g * 8];
  }
  // YA write addrs: D[m=c'][n=t1] -> YA[t1][c'], swizzled s16x4
  char* ywp[4];
  {
    const int t1 = w * 16 + c16;
    #pragma unroll
    for (int mi = 0; mi < 4; ++mi) {
      unsigned addr = t1 * 128 + mi * 32 + quad * 8;
      addr ^= (unsigned)((t1 & 7) << 4);
      ywp[mi] = (char*)YA + addr;
    }
  }
  // main-loop A frags from YA
  const short* amp[2][2];
  #pragma unroll
  for (int mi = 0; mi < 2; ++mi)
    #pragma unroll
    for (int ks = 0; ks < 2; ++ks) {
      const int row = wm + mi * 16 + c16;
      const int g = (ks * 4 + quad) ^ (row & 7);
      amp[mi][ks] = &YA[row * 64 + g * 8];
    }
  const short* bmp[4][2];
  #pragma unroll
  for (int ni = 0; ni < 4; ++ni)
    #pragma unroll
    for (int ks = 0; ks < 2; ++ks) {
      const int row = wn + ni * 16 + c16;
      const int g = (ks * 4 + quad) ^ (row & 7);
      bmp[ni][ks] = &Bs[row * 64 + g * 8];
    }

  f32x4 acc[2][4] = {};
  constexpr int NK = D_ / 64;   // 40
  for (int kk = 0; kk < NK; ++kk) {
    const int ko = kk * 64;
    __syncthreads();
    #pragma unroll
    for (int i = 0; i < 2; ++i) gl2lds16(agp[i] + ko, aldsb[i]);
    #pragma unroll
    for (int i = 0; i < 4; ++i) gl2lds16(bgp[i] + ko, bldsb[i]);
    __syncthreads();
    // B frags (Bs ready now)
    s16x8 bm[4][2];
    #pragma unroll
    for (int ni = 0; ni < 4; ++ni)
      #pragma unroll
      for (int ks = 0; ks < 2; ++ks) bm[ni][ks] = *(const s16x8*)bmp[ni][ks];
    // transform: Y = X*G for this K-slice (fresh per step, NOT accumulated)
    s16x8 xbf[2];
    #pragma unroll
    for (int ks = 0; ks < 2; ++ks) xbf[ks] = *(const s16x8*)xrp[ks];
    f32x4 y[4] = {};
    #pragma unroll
    for (int ks = 0; ks < 2; ++ks)
      #pragma unroll
      for (int mi = 0; mi < 4; ++mi)
        y[mi] = mfma16(gt[mi][ks], xbf[ks], y[mi]);
    #pragma unroll
    for (int mi = 0; mi < 4; ++mi) {
      s16x4 s4;
      #pragma unroll
      for (int r = 0; r < 4; ++r) s4[r] = f2bf(y[mi][r]);
      *(s16x4*)ywp[mi] = s4;
    }
    __syncthreads();   // YA ready
    s16x8 am[2][2];
    #pragma unroll
    for (int mi = 0; mi < 2; ++mi)
      #pragma unroll
      for (int ks = 0; ks < 2; ++ks) am[mi][ks] = *(const s16x8*)amp[mi][ks];
    #pragma unroll
    for (int ks = 0; ks < 2; ++ks)
      #pragma unroll
      for (int mi = 0; mi < 2; ++mi)
        #pragma unroll
        for (int ni = 0; ni < 4; ++ni)
          acc[mi][ni] = mfma16(am[mi][ks], bm[ni][ks], acc[mi][ni]);
  }

  // exp + per-row partial sums + atomic accumulate
  float* rsb = rowsum + b * 512;
  #pragma unroll
  for (int mi = 0; mi < 2; ++mi)
    #pragma unroll
    for (int r = 0; r < 4; ++r) {
      float part = 0.f;
      #pragma unroll
      for (int ni = 0; ni < 4; ++ni) {
        const float e0 = __expf(acc[mi][ni][r]);
        acc[mi][ni][r] = e0;
        part += e0;
      }
      #pragma unroll
      for (int mask = 1; mask < 16; mask <<= 1) part += __shfl_xor(part, mask);
      if (c16 == 0)
        atomicAdd(&rsb[m0 + wm + mi * 16 + quad * 4 + r], part);
    }

  short* ap = A + ((size_t)b * 512) * 512;
  #pragma unroll
  for (int mi = 0; mi < 2; ++mi)
    #pragma unroll
    for (int ni = 0; ni < 4; ++ni) {
      const int kcol = n0 + wn + ni * 16 + c16;
      const int qr = m0 + wm + mi * 16 + quad * 4;
      #pragma unroll
      for (int r = 0; r < 4; ++r)
        ap[(size_t)(qr + r) * 512 + kcol] = f2bf(acc[mi][ni][r]);
    }
}

// =====================================================================
// Kernel 3: out = (E @ V) * (1/rowsum).  R3-proven 128x128 tile, BK=64,
// single-buffered, grid (80,16).
// =====================================================================
__global__ __launch_bounds__(256) void pv_kernel(
    const short* __restrict__ A, const short* __restrict__ V,
    const float* __restrict__ rowsum, float* __restrict__ out)
{
  __shared__ __align__(16) short As[128 * 64];   // 16 KB
  __shared__ __align__(16) short Bs[128 * 64];   // 16 KB
  const int b = blockIdx.y;
  const int mt = blockIdx.x / 20, dt = blockIdx.x % 20;
  const int m0 = mt * 128, n0 = dt * 128;
  const int tid = threadIdx.x;
  const int w = tid >> 6, lane = tid & 63, quad = lane >> 4, c16 = lane & 15;
  const int wm = (w >> 1) * 64, wn = (w & 1) * 64;

  const short* ab = A + ((size_t)b * 512 + m0) * 512;
  const short* vb = V + ((size_t)b * D_ + n0) * 512;

  const short* agp[4]; short* aldsb[4];
  const short* bgp[4]; short* bldsb[4];
  #pragma unroll
  for (int i = 0; i < 4; ++i) {
    const int s = i * 256 + tid, row = s >> 3;
    const int g = (s & 7) ^ (row & 7);
    agp[i] = ab + (size_t)row * 512 + g * 8;
    bgp[i] = vb + (size_t)row * 512 + g * 8;
    aldsb[i] = &As[(i * 256 + w * 64) * 8];
    bldsb[i] = &Bs[(i * 256 + w * 64) * 8];
  }

  const short* amp[4][2];
  const short* bmp[4][2];
  #pragma unroll
  for (int mi = 0; mi < 4; ++mi)
    #pragma unroll
    for (int ks = 0; ks < 2; ++ks) {
      const int rowa = wm + mi * 16 + c16;
      const int rowb = wn + mi * 16 + c16;
      amp[mi][ks] = &As[rowa * 64 + (((ks * 4 + quad) ^ (rowa & 7)) * 8)];
      bmp[mi][ks] = &Bs[rowb * 64 + (((ks * 4 + quad) ^ (rowb & 7)) * 8)];
    }

  f32x4 acc[4][4] = {};
  constexpr int NK = 512 / 64;   // 8
  for (int kk = 0; kk < NK; ++kk) {
    const int ko = kk * 64;
    __syncthreads();
    #pragma unroll
    for (int i = 0; i < 4; ++i) gl2lds16(agp[i] + ko, aldsb[i]);
    #pragma unroll
    for (int i = 0; i < 4; ++i) gl2lds16(bgp[i] + ko, bldsb[i]);
    __syncthreads();
    s16x8 am[4][2], bm[4][2];
    #pragma unroll
    for (int mi = 0; mi < 4; ++mi)
      #pragma unroll
      for (int ks = 0; ks < 2; ++ks) {
        am[mi][ks] = *(const s16x8*)amp[mi][ks];
        bm[mi][ks] = *(const s16x8*)bmp[mi][ks];
      }
    #pragma unroll
    for (int ks = 0; ks < 2; ++ks)
      #pragma unroll
      for (int mi = 0; mi < 4; ++mi)
        #pragma unroll
        for (int ni = 0; ni < 4; ++ni)
          acc[mi][ni] = mfma16(am[mi][ks], bm[ni][ks], acc[mi][ni]);
  }

  // normalize rows by 1/rowsum (deferred softmax denominator)
  const float* rsb = rowsum + b * 512;
  #pragma unroll
  for (int mi = 0; mi < 4; ++mi) {
    const int t = m0 + wm + mi * 16 + quad * 4;
    const float4 rs = *(const float4*)(rsb + t);
    const float i0 = 1.0f / rs.x, i1 = 1.0f / rs.y;
    const float i2 = 1.0f / rs.z, i3 = 1.0f / rs.w;
    #pragma unroll
    for (int ni = 0; ni < 4; ++ni) {
      acc[mi][ni][0] *= i0; acc[mi][ni][1] *= i1;
      acc[mi][ni][2] *= i2; acc[mi][ni][3] *= i3;
    }
  }

  #pragma unroll
  for (int mi = 0; mi < 4; ++mi)
    #pragma unroll
    for (int ni = 0; ni < 4; ++ni) {
      const int d = n0 + wn + ni * 16 + c16;
      const int ff = d >> 6, cc = d & 63;
      const int t = m0 + wm + mi * 16 + quad * 4;
      float4 o4;
      o4.x = acc[mi][ni][0]; o4.y = acc[mi][ni][1];
      o4.z = acc[mi][ni][2]; o4.w = acc[mi][ni][3];
      *(float4*)&out[(((size_t)b * 64 + cc) * 40 + ff) * 512 + t] = o4;
    }
}

// =====================================================================
extern "C" void kernel_launch(void* const* d_in, const int* in_sizes, int n_in,
                              void* d_out, int out_size, void* d_ws, size_t ws_size,
                              hipStream_t stream)
{
  const float* x  = (const float*)d_in[0];
  const float* Wq = (const float*)d_in[1];
  const float* Wk = (const float*)d_in[2];
  const float* Wv = (const float*)d_in[3];
  float* out = (float*)d_out;

  // workspace layout (bytes):
  //   Xb  [16][512][2560] bf16 : 41,943,040   (x transposed, bf16)
  //   Vt  [16][2560][512] bf16 : 41,943,040
  //   At  [16][512][512]  bf16 :  8,388,608   (unnormalized E)
  //   Wb  Wv fragment bf16     :      8,192
  //   Gt  G^T fragment bf16    :      8,192
  //   rowsum [16][512]    fp32 :     32,768
  char* ws = (char*)d_ws;
  constexpr size_t QB = (size_t)B_ * T_ * D_ * 2;
  constexpr size_t AB = (size_t)B_ * T_ * T_ * 2;
  short* Xb = (short*)(ws);
  short* Vt = (short*)(ws + QB);
  short* At = (short*)(ws + 2 * QB);
  short* Wb = (short*)(ws + 2 * QB + AB);
  short* Gt = (short*)(ws + 2 * QB + AB + 8192);
  float* rowsum = (float*)(ws + 2 * QB + AB + 16384);

  prep_kernel<<<dim3(3), 256, 0, stream>>>(Wq, Wk, Wv, Wb, Gt, rowsum);
  proj_kernel<<<dim3(4, 40, 16), 256, 0, stream>>>(x, Wb, Xb, Vt);
  scores_kernel<<<dim3(32, 16), 256, 0, stream>>>(Xb, Gt, At, rowsum);
  pv_kernel<<<dim3(80, 16), 256, 0, stream>>>(At, Vt, rowsum, out);
}

// Round 7
// 250.281 us; speedup vs baseline: 1.0563x; 1.0563x over previous
//
#include <hip/hip_runtime.h>

// ---------- problem dims ----------
constexpr int B_ = 16, C_ = 64, F_ = 40, T_ = 512;
constexpr int D_ = F_ * C_;              // 2560
constexpr float SCALE = 0.019764235376052372f;  // 1/sqrt(2560), baked into Wq

// ---------- types ----------
typedef __attribute__((ext_vector_type(8))) short s16x8;
typedef __attribute__((ext_vector_type(4))) short s16x4;
typedef __attribute__((ext_vector_type(4))) float f32x4;

static __device__ __forceinline__ short f2bf(float f) {
  union { float f; unsigned u; } v; v.f = f;
  unsigned r = v.u + 0x7fffu + ((v.u >> 16) & 1u);   // RNE, no NaN inputs
  return (short)(r >> 16);
}

static __device__ __forceinline__ f32x4 mfma16(s16x8 a, s16x8 b, f32x4 c) {
  return __builtin_amdgcn_mfma_f32_16x16x32_bf16(a, b, c, 0, 0, 0);
}

// async 16B global->LDS (wave-uniform LDS base + lane*16 placement)
static __device__ __forceinline__ void gl2lds16(const short* g, short* l) {
  __builtin_amdgcn_global_load_lds(
      (const __attribute__((address_space(1))) unsigned int*)g,
      (__attribute__((address_space(3))) unsigned int*)l, 16, 0, 0);
}

// =====================================================================
// Kernel 0: convert Wq,Wk,Wv fp32 -> bf16 once, in PER-LANE FRAGMENT
// order so proj's wfrag loads are 1KB-contiguous (8 full lines).
// Also zeroes the rowsum accumulator (32 KB) used by scores/pv.
// =====================================================================
__global__ __launch_bounds__(256) void wcvt_kernel(
    const float* __restrict__ Wq, const float* __restrict__ Wk,
    const float* __restrict__ Wv, short* __restrict__ Wb,
    float* __restrict__ rowsum)
{
  const int n = blockIdx.x * 256 + threadIdx.x;    // 0..1535 fragment granule
  const int p = n >> 9;
  const int r = n & 511;
  const int mi = r >> 7;
  const int ks = (r >> 6) & 1;
  const int lane = r & 63;
  const int o = mi * 16 + (lane & 15);
  const int cb = ks * 32 + (lane >> 4) * 8;
  const float* src = (p == 0) ? Wq : (p == 1) ? Wk : Wv;
  const float sc = (p == 0) ? SCALE : 1.0f;
  const float4 a = *(const float4*)(src + o * 64 + cb);
  const float4 b2 = *(const float4*)(src + o * 64 + cb + 4);
  s16x8 s;
  s[0] = f2bf(a.x * sc);  s[1] = f2bf(a.y * sc);
  s[2] = f2bf(a.z * sc);  s[3] = f2bf(a.w * sc);
  s[4] = f2bf(b2.x * sc); s[5] = f2bf(b2.y * sc);
  s[6] = f2bf(b2.z * sc); s[7] = f2bf(b2.w * sc);
  *(s16x8*)&Wb[n * 8] = s;

  // zero rowsum [16][512] fp32
  for (int i = n; i < B_ * T_; i += 6 * 256) rowsum[i] = 0.0f;
}

// =====================================================================
// Kernel 1: 1x1-conv projections (R3-proven: ~62 us, full-line W loads
// + LDS-transposed full-line Q/K/V stores).
// =====================================================================
__global__ __launch_bounds__(256, 2) void proj_kernel(
    const float* __restrict__ x, const short* __restrict__ Wb,
    short* __restrict__ Q, short* __restrict__ K, short* __restrict__ V)
{
  constexpr int XS = 132;   // X lds row stride (shorts)
  __shared__ __align__(16) short Xl[64 * XS];   // 16.9 KB; reused as Ost
  char* Ost = (char*)Xl;                        // store-staging view

  const int b = blockIdx.z, f = blockIdx.y, tt = blockIdx.x;  // tt: 0..3
  const int tid = threadIdx.x;

  // ---- stage X tile [64 c][128 t] as bf16 (coalesced float4 loads) ----
  const float* xp = x + (((size_t)b * 64) * 40 + f) * 512 + tt * 128;
  #pragma unroll
  for (int it = 0; it < 8; ++it) {          // 64c x 32 float4-granules
    const int i = tid + it * 256;
    const int c = i >> 5, j = i & 31;
    const float4 v4 = *(const float4*)(xp + (size_t)c * (F_ * T_) + j * 4);
    s16x4 s4; s4[0] = f2bf(v4.x); s4[1] = f2bf(v4.y);
    s4[2] = f2bf(v4.z); s4[3] = f2bf(v4.w);
    *(s16x4*)&Xl[c * XS + j * 4] = s4;
  }
  __syncthreads();

  const int w = tid >> 6, lane = tid & 63;
  const int quad = lane >> 4, c16 = lane & 15;
  const int tl = w * 32;                    // wave's t-base within tile

  // X fragments, shared by all three projections (0-conflict reads).
  s16x8 bfrag[2][2];
  #pragma unroll
  for (int ni = 0; ni < 2; ++ni)
    #pragma unroll
    for (int ks = 0; ks < 2; ++ks) {
      const int t = tl + ni * 16 + c16;
      const int cb = ks * 32 + quad * 8;
      s16x8 tmp;
      #pragma unroll
      for (int j = 0; j < 8; ++j) tmp[j] = Xl[(cb + j) * XS + t];
      bfrag[ni][ks] = tmp;
    }
  __syncthreads();   // Xl now dead -> reusable as Ost

  #pragma unroll
  for (int p = 0; p < 3; ++p) {
    // W fragments: fully-coalesced 1KB loads
    s16x8 wfrag[4][2];
    #pragma unroll
    for (int mi = 0; mi < 4; ++mi)
      #pragma unroll
      for (int ks = 0; ks < 2; ++ks)
        wfrag[mi][ks] = *(const s16x8*)(Wb + ((p * 8 + mi * 2 + ks) * 64 + lane) * 8);

    if (p < 2) {
      // D[m=o][n=t]
      f32x4 acc[4][2] = {};
      #pragma unroll
      for (int ks = 0; ks < 2; ++ks)
        #pragma unroll
        for (int mi = 0; mi < 4; ++mi)
          #pragma unroll
          for (int ni = 0; ni < 2; ++ni)
            acc[mi][ni] = mfma16(wfrag[mi][ks], bfrag[ni][ks], acc[mi][ni]);
      __syncthreads();   // previous Ost consumers done
      // acc -> Ost[t][o], rowstride 64 shorts (128B), XOR-swizzled
      #pragma unroll
      for (int mi = 0; mi < 4; ++mi)
        #pragma unroll
        for (int ni = 0; ni < 2; ++ni) {
          const int trow = tl + ni * 16 + c16;          // 0..127
          unsigned addr = trow * 128 + (mi * 32 + quad * 8);
          addr ^= (unsigned)((trow & 7) << 4);
          s16x4 s4;
          #pragma unroll
          for (int r = 0; r < 4; ++r) s4[r] = f2bf(acc[mi][ni][r]);
          *(s16x4*)(Ost + addr) = s4;
        }
      __syncthreads();
      // cooperative store: 128 rows x 128B, 8 lanes fill one full line
      short* outp = (p == 0) ? Q : K;
      #pragma unroll
      for (int pass = 0; pass < 4; ++pass) {
        const int row = pass * 32 + (tid >> 3);
        const int s16off = tid & 7;
        unsigned a2 = row * 128 + s16off * 16;
        a2 ^= (unsigned)((row & 7) << 4);
        const s16x8 vz = *(const s16x8*)(Ost + a2);
        *(s16x8*)&outp[(size_t)(b * 512 + tt * 128 + row) * D_ + f * 64 + s16off * 8] = vz;
      }
    } else {
      // swapped: D[m=t][n=o] -> regs are 4 consecutive t
      f32x4 acc[2][4] = {};
      #pragma unroll
      for (int ks = 0; ks < 2; ++ks)
        #pragma unroll
        for (int ni = 0; ni < 2; ++ni)
          #pragma unroll
          for (int mi = 0; mi < 4; ++mi)
            acc[ni][mi] = mfma16(bfrag[ni][ks], wfrag[mi][ks], acc[ni][mi]);
      __syncthreads();
      // acc -> Ost[o][t], rowstride 128 shorts (256B), XOR-swizzled
      #pragma unroll
      for (int ni = 0; ni < 2; ++ni)
        #pragma unroll
        for (int mi = 0; mi < 4; ++mi) {
          const int orow = mi * 16 + c16;               // 0..63
          unsigned addr = orow * 256 + (tl + ni * 16 + quad * 4) * 2;
          addr ^= (unsigned)((orow & 7) << 4);
          s16x4 s4;
          #pragma unroll
          for (int r = 0; r < 4; ++r) s4[r] = f2bf(acc[ni][mi][r]);
          *(s16x4*)(Ost + addr) = s4;
        }
      __syncthreads();
      // cooperative store: 64 rows x 256B, 16 lanes fill 2 full lines
      #pragma unroll
      for (int pass = 0; pass < 4; ++pass) {
        const int row = pass * 16 + (tid >> 4);
        const int s16off = tid & 15;
        unsigned a2 = row * 256 + s16off * 16;
        a2 ^= (unsigned)((row & 7) << 4);
        const s16x8 vz = *(const s16x8*)(Ost + a2);
        *(s16x8*)&V[((size_t)(b * D_ + f * 64 + row)) * 512 + tt * 128 + s16off * 8] = vz;
      }
    }
    if (p < 2) __syncthreads();   // Ost consumed before next proj overwrites
  }
}

// =====================================================================
// Kernel 2: fused scores+softmax-numerator.  R3 structure with BK=128:
// 20 K-iterations instead of 40 -> half the barrier-drain stalls, 2x
// MFMA per barrier window.  Same traffic, same 2-blocks/CU occupancy
// (48 KB LDS).  Swizzle generalized to 16 granules/row: g ^= row&15.
// E = exp(Qs K^T) stored bf16; per-row sums atomicAdd'ed into rowsum.
// =====================================================================
__global__ __launch_bounds__(256) void scores_kernel(
    const short* __restrict__ Q, const short* __restrict__ K,
    short* __restrict__ A, float* __restrict__ rowsum)
{
  __shared__ __align__(16) short As[64 * 128];    // 16 KB
  __shared__ __align__(16) short Bs[128 * 128];   // 32 KB
  const int b = blockIdx.y;
  const int mt = blockIdx.x >> 2, nt = blockIdx.x & 3;
  const int m0 = mt * 64, n0 = nt * 128;
  const int tid = threadIdx.x;
  const int w = tid >> 6, lane = tid & 63, quad = lane >> 4, c16 = lane & 15;
  const int wm = (w >> 1) * 32, wn = (w & 1) * 64;

  const short* qb = Q + (size_t)(b * 512 + m0) * D_;
  const short* kb = K + (size_t)(b * 512 + n0) * D_;

  // staging: thread covers LDS granule s; fetches global granule
  // g = (s&15) ^ (row&15)  (16 granules of 16B per 256B row)
  const short* agp[4];
  short* aldsb[4];
  #pragma unroll
  for (int i = 0; i < 4; ++i) {
    const int s = i * 256 + tid, row = s >> 4;
    const int g = (s & 15) ^ (row & 15);
    agp[i] = qb + (size_t)row * D_ + g * 8;
    aldsb[i] = &As[(i * 256 + w * 64) * 8];
  }
  const short* bgp[8];
  short* bldsb[8];
  #pragma unroll
  for (int i = 0; i < 8; ++i) {
    const int s = i * 256 + tid, row = s >> 4;
    const int g = (s & 15) ^ (row & 15);
    bgp[i] = kb + (size_t)row * D_ + g * 8;
    bldsb[i] = &Bs[(i * 256 + w * 64) * 8];
  }

  // loop-invariant swizzled fragment addresses (ks now 0..3)
  const short* amp[2][4];
  #pragma unroll
  for (int mi = 0; mi < 2; ++mi)
    #pragma unroll
    for (int ks = 0; ks < 4; ++ks) {
      const int row = wm + mi * 16 + c16;
      const int g = (ks * 4 + quad) ^ (row & 15);
      amp[mi][ks] = &As[row * 128 + g * 8];
    }
  const short* bmp[4][4];
  #pragma unroll
  for (int ni = 0; ni < 4; ++ni)
    #pragma unroll
    for (int ks = 0; ks < 4; ++ks) {
      const int row = wn + ni * 16 + c16;
      const int g = (ks * 4 + quad) ^ (row & 15);
      bmp[ni][ks] = &Bs[row * 128 + g * 8];
    }

  f32x4 acc[2][4] = {};
  constexpr int NK = D_ / 128;   // 20
  for (int kk = 0; kk < NK; ++kk) {
    const int ko = kk * 128;
    __syncthreads();
    #pragma unroll
    for (int i = 0; i < 4; ++i) gl2lds16(agp[i] + ko, aldsb[i]);
    #pragma unroll
    for (int i = 0; i < 8; ++i) gl2lds16(bgp[i] + ko, bldsb[i]);
    __syncthreads();
    // two ks-halves to bound register pressure; addresses loop-invariant
    #pragma unroll
    for (int kh = 0; kh < 2; ++kh) {
      s16x8 am[2][2], bm[4][2];
      #pragma unroll
      for (int mi = 0; mi < 2; ++mi)
        #pragma unroll
        for (int k2 = 0; k2 < 2; ++k2)
          am[mi][k2] = *(const s16x8*)amp[mi][kh * 2 + k2];
      #pragma unroll
      for (int ni = 0; ni < 4; ++ni)
        #pragma unroll
        for (int k2 = 0; k2 < 2; ++k2)
          bm[ni][k2] = *(const s16x8*)bmp[ni][kh * 2 + k2];
      #pragma unroll
      for (int k2 = 0; k2 < 2; ++k2)
        #pragma unroll
        for (int mi = 0; mi < 2; ++mi)
          #pragma unroll
          for (int ni = 0; ni < 4; ++ni)
            acc[mi][ni] = mfma16(am[mi][k2], bm[ni][k2], acc[mi][ni]);
    }
  }

  // exp + per-row partial sums (64 cols per wave) + atomic accumulate
  float* rsb = rowsum + b * 512;
  #pragma unroll
  for (int mi = 0; mi < 2; ++mi)
    #pragma unroll
    for (int r = 0; r < 4; ++r) {
      float part = 0.f;
      #pragma unroll
      for (int ni = 0; ni < 4; ++ni) {
        const float e0 = __expf(acc[mi][ni][r]);
        acc[mi][ni][r] = e0;
        part += e0;
      }
      #pragma unroll
      for (int mask = 1; mask < 16; mask <<= 1) part += __shfl_xor(part, mask);
      if (c16 == 0)
        atomicAdd(&rsb[m0 + wm + mi * 16 + quad * 4 + r], part);
    }

  // store E as bf16 (16-lane x 2B = 32B segments, L2 merges)
  short* ap = A + ((size_t)b * 512) * 512;
  #pragma unroll
  for (int mi = 0; mi < 2; ++mi)
    #pragma unroll
    for (int ni = 0; ni < 4; ++ni) {
      const int kcol = n0 + wn + ni * 16 + c16;
      const int qr = m0 + wm + mi * 16 + quad * 4;
      #pragma unroll
      for (int r = 0; r < 4; ++r)
        ap[(size_t)(qr + r) * 512 + kcol] = f2bf(acc[mi][ni][r]);
    }
}

// =====================================================================
// Kernel 3: out = (E @ V) * (1/rowsum).  R3-proven 128x128 tile, BK=64,
// single-buffered, grid (80,16).
// =====================================================================
__global__ __launch_bounds__(256) void pv_kernel(
    const short* __restrict__ A, const short* __restrict__ V,
    const float* __restrict__ rowsum, float* __restrict__ out)
{
  __shared__ __align__(16) short As[128 * 64];   // 16 KB
  __shared__ __align__(16) short Bs[128 * 64];   // 16 KB
  const int b = blockIdx.y;
  const int mt = blockIdx.x / 20, dt = blockIdx.x % 20;
  const int m0 = mt * 128, n0 = dt * 128;
  const int tid = threadIdx.x;
  const int w = tid >> 6, lane = tid & 63, quad = lane >> 4, c16 = lane & 15;
  const int wm = (w >> 1) * 64, wn = (w & 1) * 64;

  const short* ab = A + ((size_t)b * 512 + m0) * 512;
  const short* vb = V + ((size_t)b * D_ + n0) * 512;

  const short* agp[4]; short* aldsb[4];
  const short* bgp[4]; short* bldsb[4];
  #pragma unroll
  for (int i = 0; i < 4; ++i) {
    const int s = i * 256 + tid, row = s >> 3;
    const int g = (s & 7) ^ (row & 7);
    agp[i] = ab + (size_t)row * 512 + g * 8;
    bgp[i] = vb + (size_t)row * 512 + g * 8;
    aldsb[i] = &As[(i * 256 + w * 64) * 8];
    bldsb[i] = &Bs[(i * 256 + w * 64) * 8];
  }

  const short* amp[4][2];
  const short* bmp[4][2];
  #pragma unroll
  for (int mi = 0; mi < 4; ++mi)
    #pragma unroll
    for (int ks = 0; ks < 2; ++ks) {
      const int rowa = wm + mi * 16 + c16;
      const int rowb = wn + mi * 16 + c16;
      amp[mi][ks] = &As[rowa * 64 + (((ks * 4 + quad) ^ (rowa & 7)) * 8)];
      bmp[mi][ks] = &Bs[rowb * 64 + (((ks * 4 + quad) ^ (rowb & 7)) * 8)];
    }

  f32x4 acc[4][4] = {};
  constexpr int NK = 512 / 64;   // 8
  for (int kk = 0; kk < NK; ++kk) {
    const int ko = kk * 64;
    __syncthreads();
    #pragma unroll
    for (int i = 0; i < 4; ++i) gl2lds16(agp[i] + ko, aldsb[i]);
    #pragma unroll
    for (int i = 0; i < 4; ++i) gl2lds16(bgp[i] + ko, bldsb[i]);
    __syncthreads();
    s16x8 am[4][2], bm[4][2];
    #pragma unroll
    for (int mi = 0; mi < 4; ++mi)
      #pragma unroll
      for (int ks = 0; ks < 2; ++ks) {
        am[mi][ks] = *(const s16x8*)amp[mi][ks];
        bm[mi][ks] = *(const s16x8*)bmp[mi][ks];
      }
    #pragma unroll
    for (int ks = 0; ks < 2; ++ks)
      #pragma unroll
      for (int mi = 0; mi < 4; ++mi)
        #pragma unroll
        for (int ni = 0; ni < 4; ++ni)
          acc[mi][ni] = mfma16(am[mi][ks], bm[ni][ks], acc[mi][ni]);
  }

  // normalize rows by 1/rowsum (deferred softmax denominator)
  const float* rsb = rowsum + b * 512;
  #pragma unroll
  for (int mi = 0; mi < 4; ++mi) {
    const int t = m0 + wm + mi * 16 + quad * 4;
    const float4 rs = *(const float4*)(rsb + t);
    const float i0 = 1.0f / rs.x, i1 = 1.0f / rs.y;
    const float i2 = 1.0f / rs.z, i3 = 1.0f / rs.w;
    #pragma unroll
    for (int ni = 0; ni < 4; ++ni) {
      acc[mi][ni][0] *= i0; acc[mi][ni][1] *= i1;
      acc[mi][ni][2] *= i2; acc[mi][ni][3] *= i3;
    }
  }

  #pragma unroll
  for (int mi = 0; mi < 4; ++mi)
    #pragma unroll
    for (int ni = 0; ni < 4; ++ni) {
      const int d = n0 + wn + ni * 16 + c16;
      const int ff = d >> 6, cc = d & 63;
      const int t = m0 + wm + mi * 16 + quad * 4;
      float4 o4;
      o4.x = acc[mi][ni][0]; o4.y = acc[mi][ni][1];
      o4.z = acc[mi][ni][2]; o4.w = acc[mi][ni][3];
      *(float4*)&out[(((size_t)b * 64 + cc) * 40 + ff) * 512 + t] = o4;
    }
}

// =====================================================================
extern "C" void kernel_launch(void* const* d_in, const int* in_sizes, int n_in,
                              void* d_out, int out_size, void* d_ws, size_t ws_size,
                              hipStream_t stream)
{
  const float* x  = (const float*)d_in[0];
  const float* Wq = (const float*)d_in[1];
  const float* Wk = (const float*)d_in[2];
  const float* Wv = (const float*)d_in[3];
  float* out = (float*)d_out;

  // workspace layout (bytes):
  //   Q   [16][512][2560] bf16 : 41,943,040
  //   K   [16][512][2560] bf16 : 41,943,040
  //   Vt  [16][2560][512] bf16 : 41,943,040
  //   At  [16][512][512]  bf16 :  8,388,608   (unnormalized E)
  //   Wb  fragment-ordered bf16:     24,576
  //   rowsum [16][512]    fp32 :     32,768
  char* ws = (char*)d_ws;
  constexpr size_t QB = (size_t)B_ * T_ * D_ * 2;
  constexpr size_t AB = (size_t)B_ * T_ * T_ * 2;
  short* Q  = (short*)(ws);
  short* Kt = (short*)(ws + QB);
  short* Vt = (short*)(ws + 2 * QB);
  short* At = (short*)(ws + 3 * QB);
  short* Wb = (short*)(ws + 3 * QB + AB);
  float* rowsum = (float*)(ws + 3 * QB + AB + 24576);

  wcvt_kernel<<<dim3(6), 256, 0, stream>>>(Wq, Wk, Wv, Wb, rowsum);
  proj_kernel<<<dim3(4, 40, 16), 256, 0, stream>>>(x, Wb, Q, Kt, Vt);
  scores_kernel<<<dim3(32, 16), 256, 0, stream>>>(Q, Kt, At, rowsum);
  pv_kernel<<<dim3(80, 16), 256, 0, stream>>>(At, Vt, rowsum, out);
}

// Round 8
// 248.063 us; speedup vs baseline: 1.0658x; 1.0089x over previous
//
#include <hip/hip_runtime.h>

// ---------- problem dims ----------
constexpr int B_ = 16, C_ = 64, F_ = 40, T_ = 512;
constexpr int D_ = F_ * C_;              // 2560
constexpr float SCALE = 0.019764235376052372f;  // 1/sqrt(2560), baked into Wq

// Tiled intermediate layouts (all tiles 8192 shorts = 16 KB):
//  Q',K' : [b][tt(4)][f(40)][t(128)][o(64)]
//  V'    : [b][dt(20)][tk(8)][d(128)][t(64)]
//  E'    : [b][mt(4)][kt(8)][m(128)][k(64)]

// ---------- types ----------
typedef __attribute__((ext_vector_type(8))) short s16x8;
typedef __attribute__((ext_vector_type(4))) short s16x4;
typedef __attribute__((ext_vector_type(4))) float f32x4;

static __device__ __forceinline__ short f2bf(float f) {
  union { float f; unsigned u; } v; v.f = f;
  unsigned r = v.u + 0x7fffu + ((v.u >> 16) & 1u);   // RNE, no NaN inputs
  return (short)(r >> 16);
}

static __device__ __forceinline__ f32x4 mfma16(s16x8 a, s16x8 b, f32x4 c) {
  return __builtin_amdgcn_mfma_f32_16x16x32_bf16(a, b, c, 0, 0, 0);
}

// async 16B global->LDS (wave-uniform LDS base + lane*16 placement)
static __device__ __forceinline__ void gl2lds16(const short* g, short* l) {
  __builtin_amdgcn_global_load_lds(
      (const __attribute__((address_space(1))) unsigned int*)g,
      (__attribute__((address_space(3))) unsigned int*)l, 16, 0, 0);
}

// =====================================================================
// Kernel 0: convert Wq,Wk,Wv fp32 -> bf16 once, in PER-LANE FRAGMENT
// order; zero rowsum.
// =====================================================================
__global__ __launch_bounds__(256) void wcvt_kernel(
    const float* __restrict__ Wq, const float* __restrict__ Wk,
    const float* __restrict__ Wv, short* __restrict__ Wb,
    float* __restrict__ rowsum)
{
  const int n = blockIdx.x * 256 + threadIdx.x;    // 0..1535 fragment granule
  const int p = n >> 9;
  const int r = n & 511;
  const int mi = r >> 7;
  const int ks = (r >> 6) & 1;
  const int lane = r & 63;
  const int o = mi * 16 + (lane & 15);
  const int cb = ks * 32 + (lane >> 4) * 8;
  const float* src = (p == 0) ? Wq : (p == 1) ? Wk : Wv;
  const float sc = (p == 0) ? SCALE : 1.0f;
  const float4 a = *(const float4*)(src + o * 64 + cb);
  const float4 b2 = *(const float4*)(src + o * 64 + cb + 4);
  s16x8 s;
  s[0] = f2bf(a.x * sc);  s[1] = f2bf(a.y * sc);
  s[2] = f2bf(a.z * sc);  s[3] = f2bf(a.w * sc);
  s[4] = f2bf(b2.x * sc); s[5] = f2bf(b2.y * sc);
  s[6] = f2bf(b2.z * sc); s[7] = f2bf(b2.w * sc);
  *(s16x8*)&Wb[n * 8] = s;

  for (int i = n; i < B_ * T_; i += 6 * 256) rowsum[i] = 0.0f;
}

// =====================================================================
// Kernel 1: 1x1-conv projections (R3 datapaths; v9: tile-contiguous
// output layouts -> every cooperative store is a contiguous 16KB stream).
// =====================================================================
__global__ __launch_bounds__(256, 2) void proj_kernel(
    const float* __restrict__ x, const short* __restrict__ Wb,
    short* __restrict__ Q, short* __restrict__ K, short* __restrict__ V)
{
  constexpr int XS = 132;   // X lds row stride (shorts)
  __shared__ __align__(16) short Xl[64 * XS];   // 16.9 KB; reused as Ost
  char* Ost = (char*)Xl;                        // store-staging view

  const int b = blockIdx.z, f = blockIdx.y, tt = blockIdx.x;  // tt: 0..3
  const int tid = threadIdx.x;

  // ---- stage X tile [64 c][128 t] as bf16 (coalesced float4 loads) ----
  const float* xp = x + (((size_t)b * 64) * 40 + f) * 512 + tt * 128;
  #pragma unroll
  for (int it = 0; it < 8; ++it) {          // 64c x 32 float4-granules
    const int i = tid + it * 256;
    const int c = i >> 5, j = i & 31;
    const float4 v4 = *(const float4*)(xp + (size_t)c * (F_ * T_) + j * 4);
    s16x4 s4; s4[0] = f2bf(v4.x); s4[1] = f2bf(v4.y);
    s4[2] = f2bf(v4.z); s4[3] = f2bf(v4.w);
    *(s16x4*)&Xl[c * XS + j * 4] = s4;
  }
  __syncthreads();

  const int w = tid >> 6, lane = tid & 63;
  const int quad = lane >> 4, c16 = lane & 15;
  const int tl = w * 32;                    // wave's t-base within tile

  // X fragments, shared by all three projections (0-conflict reads).
  s16x8 bfrag[2][2];
  #pragma unroll
  for (int ni = 0; ni < 2; ++ni)
    #pragma unroll
    for (int ks = 0; ks < 2; ++ks) {
      const int t = tl + ni * 16 + c16;
      const int cb = ks * 32 + quad * 8;
      s16x8 tmp;
      #pragma unroll
      for (int j = 0; j < 8; ++j) tmp[j] = Xl[(cb + j) * XS + t];
      bfrag[ni][ks] = tmp;
    }
  __syncthreads();   // Xl now dead -> reusable as Ost

  #pragma unroll
  for (int p = 0; p < 3; ++p) {
    // W fragments: fully-coalesced 1KB loads
    s16x8 wfrag[4][2];
    #pragma unroll
    for (int mi = 0; mi < 4; ++mi)
      #pragma unroll
      for (int ks = 0; ks < 2; ++ks)
        wfrag[mi][ks] = *(const s16x8*)(Wb + ((p * 8 + mi * 2 + ks) * 64 + lane) * 8);

    if (p < 2) {
      // D[m=o][n=t]
      f32x4 acc[4][2] = {};
      #pragma unroll
      for (int ks = 0; ks < 2; ++ks)
        #pragma unroll
        for (int mi = 0; mi < 4; ++mi)
          #pragma unroll
          for (int ni = 0; ni < 2; ++ni)
            acc[mi][ni] = mfma16(wfrag[mi][ks], bfrag[ni][ks], acc[mi][ni]);
      __syncthreads();   // previous Ost consumers done
      // acc -> Ost[t][o], rowstride 64 shorts (128B), XOR-swizzled
      #pragma unroll
      for (int mi = 0; mi < 4; ++mi)
        #pragma unroll
        for (int ni = 0; ni < 2; ++ni) {
          const int trow = tl + ni * 16 + c16;          // 0..127
          unsigned addr = trow * 128 + (mi * 32 + quad * 8);
          addr ^= (unsigned)((trow & 7) << 4);
          s16x4 s4;
          #pragma unroll
          for (int r = 0; r < 4; ++r) s4[r] = f2bf(acc[mi][ni][r]);
          *(s16x4*)(Ost + addr) = s4;
        }
      __syncthreads();
      // cooperative store into Q'/K' tile: CONTIGUOUS 16 KB
      short* tb = ((p == 0) ? Q : K) + ((size_t)((b * 4 + tt) * 40 + f)) * 8192;
      #pragma unroll
      for (int pass = 0; pass < 4; ++pass) {
        const int row = pass * 32 + (tid >> 3);         // t 0..127
        const int s16off = tid & 7;                     // o-granule
        unsigned a2 = row * 128 + s16off * 16;
        a2 ^= (unsigned)((row & 7) << 4);
        const s16x8 vz = *(const s16x8*)(Ost + a2);
        *(s16x8*)&tb[row * 64 + s16off * 8] = vz;
      }
    } else {
      // swapped: D[m=t][n=o] -> regs are 4 consecutive t
      f32x4 acc[2][4] = {};
      #pragma unroll
      for (int ks = 0; ks < 2; ++ks)
        #pragma unroll
        for (int ni = 0; ni < 2; ++ni)
          #pragma unroll
          for (int mi = 0; mi < 4; ++mi)
            acc[ni][mi] = mfma16(bfrag[ni][ks], wfrag[mi][ks], acc[ni][mi]);
      __syncthreads();
      // acc -> Ost[o][t], rowstride 128 shorts (256B), XOR-swizzled
      #pragma unroll
      for (int ni = 0; ni < 2; ++ni)
        #pragma unroll
        for (int mi = 0; mi < 4; ++mi) {
          const int orow = mi * 16 + c16;               // 0..63
          unsigned addr = orow * 256 + (tl + ni * 16 + quad * 4) * 2;
          addr ^= (unsigned)((orow & 7) << 4);
          s16x4 s4;
          #pragma unroll
          for (int r = 0; r < 4; ++r) s4[r] = f2bf(acc[ni][mi][r]);
          *(s16x4*)(Ost + addr) = s4;
        }
      __syncthreads();
      // cooperative store into V' tiles: two contiguous 8KB halves
      // V'[(b*20 + f/2)][tk = tt*2 + h][d = (f&1)*64 + orow][t(64)]
      const size_t vbase = (((size_t)(b * 20 + (f >> 1)) * 8) + tt * 2) * 8192
                         + (size_t)((f & 1) * 64) * 64;
      #pragma unroll
      for (int pass = 0; pass < 4; ++pass) {
        const int row = pass * 16 + (tid >> 4);         // orow 0..63
        const int s16off = tid & 15;                    // t-granule 0..15
        unsigned a2 = row * 256 + s16off * 16;
        a2 ^= (unsigned)((row & 7) << 4);
        const s16x8 vz = *(const s16x8*)(Ost + a2);
        const int h = s16off >> 3;                      // tk half
        const int tg = s16off & 7;
        *(s16x8*)&V[vbase + (size_t)h * 8192 + row * 64 + tg * 8] = vz;
      }
    }
    if (p < 2) __syncthreads();   // Ost consumed before next proj overwrites
  }
}

// =====================================================================
// Kernel 2: fused scores+softmax-numerator (R3 geometry: 64x128, BK=64,
// 2-barrier loop).  v9: tiled Q'/K' inputs -> staging per K-iter is one
// contiguous 8KB (A) + 16KB (B) stream.  E written to tiled E'.
// =====================================================================
__global__ __launch_bounds__(256) void scores_kernel(
    const short* __restrict__ Q, const short* __restrict__ K,
    short* __restrict__ A, float* __restrict__ rowsum)
{
  __shared__ __align__(16) short As[64 * 64];    // 8 KB
  __shared__ __align__(16) short Bs[128 * 64];   // 16 KB
  const int b = blockIdx.y;
  const int mt = blockIdx.x >> 2, nt = blockIdx.x & 3;   // mt 0..7, nt 0..3
  const int m0 = mt * 64, n0 = nt * 128;
  const int tid = threadIdx.x;
  const int w = tid >> 6, lane = tid & 63, quad = lane >> 4, c16 = lane & 15;
  const int wm = (w >> 1) * 32, wn = (w & 1) * 64;

  // A-panel: rows m0..m0+63 live in Q' tile tt=mt>>1 at t-offset (mt&1)*64
  const short* qb = Q + ((size_t)((b * 4 + (mt >> 1)) * 40)) * 8192
                      + (size_t)((mt & 1) * 64) * 64;
  // B-panel: rows n0..n0+127 = exactly K' tile tt=nt
  const short* kb = K + ((size_t)((b * 4 + nt) * 40)) * 8192;

  // staging (swizzled placement; row stride 64 shorts)
  const short* agp[2]; short* aldsb[2];
  #pragma unroll
  for (int i = 0; i < 2; ++i) {
    const int s = i * 256 + tid, row = s >> 3;
    const int g = (s & 7) ^ (row & 7);
    agp[i] = qb + row * 64 + g * 8;
    aldsb[i] = &As[(i * 256 + w * 64) * 8];
  }
  const short* bgp[4]; short* bldsb[4];
  #pragma unroll
  for (int i = 0; i < 4; ++i) {
    const int s = i * 256 + tid, row = s >> 3;
    const int g = (s & 7) ^ (row & 7);
    bgp[i] = kb + row * 64 + g * 8;
    bldsb[i] = &Bs[(i * 256 + w * 64) * 8];
  }

  const short* amp[2][2];
  #pragma unroll
  for (int mi = 0; mi < 2; ++mi)
    #pragma unroll
    for (int ks = 0; ks < 2; ++ks) {
      const int row = wm + mi * 16 + c16;
      const int g = (ks * 4 + quad) ^ (row & 7);
      amp[mi][ks] = &As[row * 64 + g * 8];
    }
  const short* bmp[4][2];
  #pragma unroll
  for (int ni = 0; ni < 4; ++ni)
    #pragma unroll
    for (int ks = 0; ks < 2; ++ks) {
      const int row = wn + ni * 16 + c16;
      const int g = (ks * 4 + quad) ^ (row & 7);
      bmp[ni][ks] = &Bs[row * 64 + g * 8];
    }

  f32x4 acc[2][4] = {};
  constexpr int NK = D_ / 64;   // 40 (one f per K-iter; tile step 8192)
  for (int kk = 0; kk < NK; ++kk) {
    const size_t ko = (size_t)kk * 8192;
    __syncthreads();
    #pragma unroll
    for (int i = 0; i < 2; ++i) gl2lds16(agp[i] + ko, aldsb[i]);
    #pragma unroll
    for (int i = 0; i < 4; ++i) gl2lds16(bgp[i] + ko, bldsb[i]);
    __syncthreads();
    s16x8 am[2][2], bm[4][2];
    #pragma unroll
    for (int mi = 0; mi < 2; ++mi)
      #pragma unroll
      for (int ks = 0; ks < 2; ++ks) am[mi][ks] = *(const s16x8*)amp[mi][ks];
    #pragma unroll
    for (int ni = 0; ni < 4; ++ni)
      #pragma unroll
      for (int ks = 0; ks < 2; ++ks) bm[ni][ks] = *(const s16x8*)bmp[ni][ks];
    #pragma unroll
    for (int ks = 0; ks < 2; ++ks)
      #pragma unroll
      for (int mi = 0; mi < 2; ++mi)
        #pragma unroll
        for (int ni = 0; ni < 4; ++ni)
          acc[mi][ni] = mfma16(am[mi][ks], bm[ni][ks], acc[mi][ni]);
  }

  // exp + per-row partial sums + atomic accumulate
  float* rsb = rowsum + b * 512;
  #pragma unroll
  for (int mi = 0; mi < 2; ++mi)
    #pragma unroll
    for (int r = 0; r < 4; ++r) {
      float part = 0.f;
      #pragma unroll
      for (int ni = 0; ni < 4; ++ni) {
        const float e0 = __expf(acc[mi][ni][r]);
        acc[mi][ni][r] = e0;
        part += e0;
      }
      #pragma unroll
      for (int mask = 1; mask < 16; mask <<= 1) part += __shfl_xor(part, mask);
      if (c16 == 0)
        atomicAdd(&rsb[m0 + wm + mi * 16 + quad * 4 + r], part);
    }

  // store E into tiled E': [b][mt>>1][kt][m(128)][k(64)]
  short* ap = A + ((size_t)(b * 4 + (mt >> 1)) * 8) * 8192
                + (size_t)((mt & 1) * 64) * 64;
  const int ktb = nt * 2 + (wn >> 6);
  #pragma unroll
  for (int mi = 0; mi < 2; ++mi)
    #pragma unroll
    for (int ni = 0; ni < 4; ++ni) {
      const int kc = ni * 16 + c16;                 // 0..63 within kt
      const int mr = wm + mi * 16 + quad * 4;       // + r
      #pragma unroll
      for (int r = 0; r < 4; ++r)
        ap[(size_t)ktb * 8192 + (mr + r) * 64 + kc] = f2bf(acc[mi][ni][r]);
    }
}

// =====================================================================
// Kernel 3: out = (E @ V) * (1/rowsum).  R3 geometry (128x128, BK=64,
// single-buffered).  v9: tiled E'/V' inputs -> both staging streams are
// contiguous 16KB per K-iter.
// =====================================================================
__global__ __launch_bounds__(256) void pv_kernel(
    const short* __restrict__ A, const short* __restrict__ V,
    const float* __restrict__ rowsum, float* __restrict__ out)
{
  __shared__ __align__(16) short As[128 * 64];   // 16 KB
  __shared__ __align__(16) short Bs[128 * 64];   // 16 KB
  const int b = blockIdx.y;
  const int mt = blockIdx.x / 20, dt = blockIdx.x % 20;
  const int m0 = mt * 128, n0 = dt * 128;
  const int tid = threadIdx.x;
  const int w = tid >> 6, lane = tid & 63, quad = lane >> 4, c16 = lane & 15;
  const int wm = (w >> 1) * 64, wn = (w & 1) * 64;

  const short* ab = A + ((size_t)(b * 4 + mt) * 8) * 8192;
  const short* vb = V + ((size_t)(b * 20 + dt) * 8) * 8192;

  const short* agp[4]; short* aldsb[4];
  const short* bgp[4]; short* bldsb[4];
  #pragma unroll
  for (int i = 0; i < 4; ++i) {
    const int s = i * 256 + tid, row = s >> 3;
    const int g = (s & 7) ^ (row & 7);
    agp[i] = ab + row * 64 + g * 8;
    bgp[i] = vb + row * 64 + g * 8;
    aldsb[i] = &As[(i * 256 + w * 64) * 8];
    bldsb[i] = &Bs[(i * 256 + w * 64) * 8];
  }

  const short* amp[4][2];
  const short* bmp[4][2];
  #pragma unroll
  for (int mi = 0; mi < 4; ++mi)
    #pragma unroll
    for (int ks = 0; ks < 2; ++ks) {
      const int rowa = wm + mi * 16 + c16;
      const int rowb = wn + mi * 16 + c16;
      amp[mi][ks] = &As[rowa * 64 + (((ks * 4 + quad) ^ (rowa & 7)) * 8)];
      bmp[mi][ks] = &Bs[rowb * 64 + (((ks * 4 + quad) ^ (rowb & 7)) * 8)];
    }

  f32x4 acc[4][4] = {};
  constexpr int NK = 512 / 64;   // 8 kt tiles
  for (int kk = 0; kk < NK; ++kk) {
    const size_t ko = (size_t)kk * 8192;
    __syncthreads();
    #pragma unroll
    for (int i = 0; i < 4; ++i) gl2lds16(agp[i] + ko, aldsb[i]);
    #pragma unroll
    for (int i = 0; i < 4; ++i) gl2lds16(bgp[i] + ko, bldsb[i]);
    __syncthreads();
    s16x8 am[4][2], bm[4][2];
    #pragma unroll
    for (int mi = 0; mi < 4; ++mi)
      #pragma unroll
      for (int ks = 0; ks < 2; ++ks) {
        am[mi][ks] = *(const s16x8*)amp[mi][ks];
        bm[mi][ks] = *(const s16x8*)bmp[mi][ks];
      }
    #pragma unroll
    for (int ks = 0; ks < 2; ++ks)
      #pragma unroll
      for (int mi = 0; mi < 4; ++mi)
        #pragma unroll
        for (int ni = 0; ni < 4; ++ni)
          acc[mi][ni] = mfma16(am[mi][ks], bm[ni][ks], acc[mi][ni]);
  }

  // normalize rows by 1/rowsum (deferred softmax denominator)
  const float* rsb = rowsum + b * 512;
  #pragma unroll
  for (int mi = 0; mi < 4; ++mi) {
    const int t = m0 + wm + mi * 16 + quad * 4;
    const float4 rs = *(const float4*)(rsb + t);
    const float i0 = 1.0f / rs.x, i1 = 1.0f / rs.y;
    const float i2 = 1.0f / rs.z, i3 = 1.0f / rs.w;
    #pragma unroll
    for (int ni = 0; ni < 4; ++ni) {
      acc[mi][ni][0] *= i0; acc[mi][ni][1] *= i1;
      acc[mi][ni][2] *= i2; acc[mi][ni][3] *= i3;
    }
  }

  #pragma unroll
  for (int mi = 0; mi < 4; ++mi)
    #pragma unroll
    for (int ni = 0; ni < 4; ++ni) {
      const int d = n0 + wn + ni * 16 + c16;
      const int ff = d >> 6, cc = d & 63;
      const int t = m0 + wm + mi * 16 + quad * 4;
      float4 o4;
      o4.x = acc[mi][ni][0]; o4.y = acc[mi][ni][1];
      o4.z = acc[mi][ni][2]; o4.w = acc[mi][ni][3];
      *(float4*)&out[(((size_t)b * 64 + cc) * 40 + ff) * 512 + t] = o4;
    }
}

// =====================================================================
extern "C" void kernel_launch(void* const* d_in, const int* in_sizes, int n_in,
                              void* d_out, int out_size, void* d_ws, size_t ws_size,
                              hipStream_t stream)
{
  const float* x  = (const float*)d_in[0];
  const float* Wq = (const float*)d_in[1];
  const float* Wk = (const float*)d_in[2];
  const float* Wv = (const float*)d_in[3];
  float* out = (float*)d_out;

  // workspace layout (bytes):
  //   Q'  tiled bf16           : 41,943,040
  //   K'  tiled bf16           : 41,943,040
  //   V'  tiled bf16           : 41,943,040
  //   E'  tiled bf16           :  8,388,608
  //   Wb  fragment-ordered bf16:     24,576
  //   rowsum [16][512]    fp32 :     32,768
  char* ws = (char*)d_ws;
  constexpr size_t QB = (size_t)B_ * T_ * D_ * 2;
  constexpr size_t AB = (size_t)B_ * T_ * T_ * 2;
  short* Q  = (short*)(ws);
  short* Kt = (short*)(ws + QB);
  short* Vt = (short*)(ws + 2 * QB);
  short* At = (short*)(ws + 3 * QB);
  short* Wb = (short*)(ws + 3 * QB + AB);
  float* rowsum = (float*)(ws + 3 * QB + AB + 24576);

  wcvt_kernel<<<dim3(6), 256, 0, stream>>>(Wq, Wk, Wv, Wb, rowsum);
  proj_kernel<<<dim3(4, 40, 16), 256, 0, stream>>>(x, Wb, Q, Kt, Vt);
  scores_kernel<<<dim3(32, 16), 256, 0, stream>>>(Q, Kt, At, rowsum);
  pv_kernel<<<dim3(80, 16), 256, 0, stream>>>(At, Vt, rowsum, out);
}